// Round 5
// baseline (330.524 us; speedup 1.0000x reference)
//
#include <hip/hip_runtime.h>
#include <stdint.h>

#define B_N 16
#define C_N 512
#define S_N 1024
#define G_N 32
#define NH  8
#define HD  64

typedef __attribute__((ext_vector_type(8))) short bf16x8;
typedef __attribute__((ext_vector_type(4))) float f32x4;
typedef __attribute__((ext_vector_type(16))) float f32x16;
typedef unsigned short u16;
typedef unsigned int   u32;
typedef __attribute__((ext_vector_type(4))) u16 u16x4;
typedef __attribute__((ext_vector_type(4))) u32 u32x4;

__device__ __forceinline__ u16 f2bf(float f) {
  u32 u = __builtin_bit_cast(u32, f);
  u32 r = (u + 0x7fffu + ((u >> 16) & 1u)) >> 16;   // RNE
  return (u16)r;
}

__device__ __forceinline__ u32 pkbf(float a, float b) {
  return (u32)f2bf(a) | ((u32)f2bf(b) << 16);       // a -> low 16, b -> high 16
}

__device__ __forceinline__ void gll16(const void* g, void* l) {
  __builtin_amdgcn_global_load_lds((const __attribute__((address_space(1))) u32*)g,
                                   (__attribute__((address_space(3))) u32*)l, 16, 0, 0);
}

// ---------------- GroupNorm stats: one block per (b,g) ----------------
__global__ __launch_bounds__(256) void gn_stats(const float* __restrict__ x,
                                                float* __restrict__ stats) {
  const int bg = blockIdx.x;                    // b*32+g
  const float4* xv = (const float4*)(x + (size_t)bg * (16 * S_N));
  float s = 0.f, ss = 0.f;
  for (int i = threadIdx.x; i < 4096; i += 256) {
    float4 v = xv[i];
    s  += v.x + v.y + v.z + v.w;
    ss += v.x*v.x + v.y*v.y + v.z*v.z + v.w*v.w;
  }
  #pragma unroll
  for (int m = 1; m < 64; m <<= 1) { s += __shfl_xor(s, m); ss += __shfl_xor(ss, m); }
  __shared__ float red[2][4];
  const int wid = threadIdx.x >> 6;
  if ((threadIdx.x & 63) == 0) { red[0][wid] = s; red[1][wid] = ss; }
  __syncthreads();
  if (threadIdx.x == 0) {
    float S1 = red[0][0]+red[0][1]+red[0][2]+red[0][3];
    float S2 = red[1][0]+red[1][1]+red[1][2]+red[1][3];
    float mean = S1 * (1.f/16384.f);
    float var  = S2 * (1.f/16384.f) - mean*mean;
    stats[bg*2]   = mean;
    stats[bg*2+1] = rsqrtf(var + 1e-5f);
  }
}

// ------------- normalize + transpose -> h_t[b][s][c] (bf16) -------------
__global__ __launch_bounds__(256) void gn_apply_t(const float* __restrict__ x,
                                                  const float* __restrict__ stats,
                                                  const float* __restrict__ nw,
                                                  const float* __restrict__ nb,
                                                  u16* __restrict__ h_t) {
  const int c0 = blockIdx.x * 32, s0 = blockIdx.y * 64, b = blockIdx.z;
  __shared__ u16 tile[32][68];
  const int t = threadIdx.x;
  #pragma unroll
  for (int i = 0; i < 2; i++) {
    int idx4 = (i*256 + t) * 4;
    int cr = idx4 >> 6, sr = idx4 & 63;
    int c = c0 + cr;
    float4 v = *(const float4*)&x[((size_t)b*C_N + c)*S_N + s0 + sr];
    int bg = b*G_N + (c >> 4);
    float mean = stats[bg*2], rstd = stats[bg*2+1];
    float w = nw[c]*rstd;
    float bb = nb[c] - mean*w;
    tile[cr][sr]   = f2bf(v.x*w + bb);
    tile[cr][sr+1] = f2bf(v.y*w + bb);
    tile[cr][sr+2] = f2bf(v.z*w + bb);
    tile[cr][sr+3] = f2bf(v.w*w + bb);
  }
  __syncthreads();
  #pragma unroll
  for (int i = 0; i < 2; i++) {
    int idx = i*256 + t;
    int sr = idx >> 3;
    int cr4 = (idx & 7) * 4;
    u16x4 v = { tile[cr4][sr], tile[cr4+1][sr], tile[cr4+2][sr], tile[cr4+3][sr] };
    *(u16x4*)&h_t[((size_t)b*S_N + s0 + sr)*C_N + c0 + cr4] = v;
  }
}

// ---------------- fp32 -> bf16 weight convert ----------------
__global__ __launch_bounds__(256) void cvt_bf16_k(const float* __restrict__ src,
                                                  u16* __restrict__ dst, int n4) {
  int i = blockIdx.x*256 + threadIdx.x;
  if (i < n4) {
    float4 v = ((const float4*)src)[i];
    u16x4 r = { f2bf(v.x), f2bf(v.y), f2bf(v.z), f2bf(v.w) };
    ((u16x4*)dst)[i] = r;
  }
}

// ---------------- GEMM-1: qkv = h_t @ qkv_w^T, scatter to Q/K/V packs ----------------
__global__ __launch_bounds__(256) void gemm_qkv(const u16* __restrict__ h_t,
                                                const u16* __restrict__ wq,
                                                const float* __restrict__ bq,
                                                u16* __restrict__ Qp,
                                                u16* __restrict__ Kp,
                                                u16* __restrict__ Vp) {
  __shared__ u16 Ash[128*32];
  __shared__ u16 Bsh[128*32];
  const int n0 = blockIdx.x*128, m0 = blockIdx.y*128, b = blockIdx.z;
  const int tid = threadIdx.x, wid = tid >> 6, lane = tid & 63;
  const int wm = wid >> 1, wn = wid & 1;
  const u16* Ag = h_t + (size_t)b*S_N*C_N;
  const f32x4 vzero = {0.f,0.f,0.f,0.f};
  f32x4 acc[4][4];
  #pragma unroll
  for (int i=0;i<4;i++)
    #pragma unroll
    for (int j=0;j<4;j++) acc[i][j] = vzero;

  const int arow = lane >> 2, aslot = (lane & 3) * 8;
  for (int k0 = 0; k0 < C_N; k0 += 32) {
    __syncthreads();
    #pragma unroll
    for (int i = 0; i < 2; i++) {
      int r = wid*32 + i*16 + arow;
      gll16(Ag + (size_t)(m0+r)*C_N + k0 + aslot, &Ash[(wid*32+i*16)*32]);
      gll16(wq + (size_t)(n0+r)*C_N + k0 + aslot, &Bsh[(wid*32+i*16)*32]);
    }
    __syncthreads();
    bf16x8 aF[4], bF[4];
    #pragma unroll
    for (int mi=0;mi<4;mi++)
      aF[mi] = *(const bf16x8*)&Ash[(wm*64+mi*16+(lane&15))*32 + (lane>>4)*8];
    #pragma unroll
    for (int ni=0;ni<4;ni++)
      bF[ni] = *(const bf16x8*)&Bsh[(wn*64+ni*16+(lane&15))*32 + (lane>>4)*8];
    #pragma unroll
    for (int mi=0;mi<4;mi++)
      #pragma unroll
      for (int ni=0;ni<4;ni++)
        acc[mi][ni] = __builtin_amdgcn_mfma_f32_16x16x32_bf16(aF[mi], bF[ni], acc[mi][ni], 0, 0, 0);
  }

  #pragma unroll
  for (int mi=0;mi<4;mi++) {
    #pragma unroll
    for (int ni=0;ni<4;ni++) {
      int o = n0 + wn*64 + ni*16 + (lane & 15);
      float bias = bq[o];
      int sec = o >> 9;
      int oo  = o & 511;
      int hh  = oo >> 6, d = oo & 63;
      size_t bh = (size_t)(b*NH + hh);
      #pragma unroll
      for (int r=0;r<4;r++) {
        int s = m0 + wm*64 + mi*16 + (lane>>4)*4 + r;
        u16 bv = f2bf(acc[mi][ni][r] + bias);
        if (sec == 0)      Qp[(bh*S_N + s)*HD + d] = bv;
        else if (sec == 1) Kp[(bh*S_N + s)*HD + d] = bv;
        else               Vp[(bh*HD + d)*S_N + s] = bv;
      }
    }
  }
}

// ---------------- flash attention, swapped-operand 32x32 structure ----------------
// Per wave: 32 q-rows. S^T = mfma(K_frag, Q_frag) -> lane owns s = lane&31,
// t-halves split across lane pair (l, l+32). O^T = mfma(V^T_frag, P^T_frag):
// cols = s = lane&31 -> alpha rescale is a per-lane scalar. No LDS, no barriers.
__global__ __launch_bounds__(256) void attn_fwd(const u16* __restrict__ Qp,
                                                const u16* __restrict__ Kp,
                                                const u16* __restrict__ Vp,
                                                u16* __restrict__ at) {
  const int hh = blockIdx.x, q0 = blockIdx.y*128, b = blockIdx.z;
  const int tid = threadIdx.x, wid = tid >> 6, lane = tid & 63;
  const int l31 = lane & 31, hi = lane >> 5;
  const size_t bh = (size_t)(b*NH + hh);
  const u16* Qb = Qp + bh*(S_N*HD);
  const u16* Kb = Kp + bh*(S_N*HD);
  const u16* Vb = Vp + bh*(HD*S_N);
  const int s = q0 + wid*32 + l31;          // this lane's s-row

  // Q B-fragments: Q[s][kt*16 + hi*8 + j]
  bf16x8 qf[4];
  #pragma unroll
  for (int kt=0;kt<4;kt++)
    qf[kt] = *(const bf16x8*)&Qb[(size_t)s*HD + kt*16 + hi*8];

  f32x16 oacc[2];
  #pragma unroll
  for (int dt=0;dt<2;dt++)
    #pragma unroll
    for (int i=0;i<16;i++) oacc[dt][i] = 0.f;
  float m_run = -1e30f, l_run = 0.f;
  const float SC2 = 0.18033688011112042f;   // (1/sqrt(64)) * log2(e)

  for (int t0 = 0; t0 < S_N; t0 += 64) {
    // S^T tiles: st[tt][reg] = S[t][s], t = (reg&3)+8*(reg>>2)+4*hi + 32*tt
    f32x16 st[2];
    #pragma unroll
    for (int tt=0;tt<2;tt++)
      #pragma unroll
      for (int i=0;i<16;i++) st[tt][i] = 0.f;
    #pragma unroll
    for (int tt=0;tt<2;tt++)
      #pragma unroll
      for (int kt=0;kt<4;kt++) {
        bf16x8 kF = *(const bf16x8*)&Kb[(size_t)(t0 + tt*32 + l31)*HD + kt*16 + hi*8];
        st[tt] = __builtin_amdgcn_mfma_f32_32x32x16_bf16(kF, qf[kt], st[tt], 0, 0, 0);
      }

    // row max over 64 t (own 32 + partner 32)
    float mx[16];
    #pragma unroll
    for (int i=0;i<16;i++) mx[i] = fmaxf(st[0][i], st[1][i]);
    #pragma unroll
    for (int off=8; off; off>>=1)
      #pragma unroll
      for (int i=0;i<8;i++) if (i < off) mx[i] = fmaxf(mx[i], mx[i+off]);
    float tmax = fmaxf(mx[0], __shfl_xor(mx[0], 32));
    float mnew  = fmaxf(m_run, tmax);
    float alpha = exp2f((m_run - mnew) * SC2);
    m_run = mnew;
    float mc = mnew * SC2;

    // p[tt*16+reg] = exp2(S*SC2 - mc)
    float p[32];
    #pragma unroll
    for (int tt=0;tt<2;tt++)
      #pragma unroll
      for (int i=0;i<16;i++)
        p[tt*16+i] = exp2f(fmaf(st[tt][i], SC2, -mc));

    // row sum
    float sm[16];
    #pragma unroll
    for (int i=0;i<16;i++) sm[i] = p[i] + p[16+i];
    #pragma unroll
    for (int off=8; off; off>>=1)
      #pragma unroll
      for (int i=0;i<8;i++) if (i < off) sm[i] += sm[i+off];
    float rs = sm[0] + __shfl_xor(sm[0], 32);
    l_run = l_run*alpha + rs;

    #pragma unroll
    for (int dt=0;dt<2;dt++)
      #pragma unroll
      for (int i=0;i<16;i++) oacc[dt][i] *= alpha;

    // assemble P^T B-fragments in-register:
    // pa[ks] elem j <-> t = ks*16 + hi*8 + j.
    // j0-3: hi0 -> own p[8ks..8ks+3]; hi1 -> partner p[8ks+4..8ks+7]
    // j4-7: hi0 -> partner p[8ks..8ks+3]; hi1 -> own p[8ks+4..8ks+7]
    u32x4 paw[4];
    #pragma unroll
    for (int ks=0;ks<4;ks++) {
      u32 w0 = pkbf(p[8*ks+0], p[8*ks+1]);
      u32 w1 = pkbf(p[8*ks+2], p[8*ks+3]);
      u32 w2 = pkbf(p[8*ks+4], p[8*ks+5]);
      u32 w3 = pkbf(p[8*ks+6], p[8*ks+7]);
      u32 x0 = (u32)__shfl_xor((int)w2, 32);
      u32 x1 = (u32)__shfl_xor((int)w3, 32);
      u32 x2 = (u32)__shfl_xor((int)w0, 32);
      u32 x3 = (u32)__shfl_xor((int)w1, 32);
      u32x4 w = { hi ? x0 : w0, hi ? x1 : w1, hi ? w2 : x2, hi ? w3 : x3 };
      paw[ks] = w;
    }

    // O^T[dt] += sum_ks V^T_frag(dt,ks) * pa[ks]
    #pragma unroll
    for (int dt=0;dt<2;dt++)
      #pragma unroll
      for (int ks=0;ks<4;ks++) {
        bf16x8 vF = *(const bf16x8*)&Vb[(size_t)(dt*32 + l31)*S_N + t0 + ks*16 + hi*8];
        oacc[dt] = __builtin_amdgcn_mfma_f32_32x32x16_bf16(vF, __builtin_bit_cast(bf16x8, paw[ks]), oacc[dt], 0, 0, 0);
      }
  }

  // epilogue: O^T[d][s]/l -> at[b][s][h*64+d]; d = (reg&3)+8*(reg>>2)+4*hi+32*dt
  float inv = 1.0f / l_run;
  #pragma unroll
  for (int dt=0;dt<2;dt++)
    #pragma unroll
    for (int qd=0;qd<4;qd++) {
      int dbase = 4*hi + 8*qd + 32*dt;
      u16x4 o;
      #pragma unroll
      for (int j=0;j<4;j++) o[j] = f2bf(oacc[dt][qd*4+j] * inv);
      *(u16x4*)&at[((size_t)b*S_N + s)*C_N + hh*HD + dbase] = o;
    }
}

// ---------------- GEMM-2: out = proj_w @ attn + bias + x ----------------
__global__ __launch_bounds__(256) void gemm_proj(const u16* __restrict__ pwb,
                                                 const u16* __restrict__ at,
                                                 const float* __restrict__ bp,
                                                 const float* __restrict__ x,
                                                 float* __restrict__ out) {
  __shared__ u16 Ash[128*32];
  __shared__ u16 Bsh[128*32];
  const int n0 = blockIdx.x*128, m0 = blockIdx.y*128, b = blockIdx.z;
  const int tid = threadIdx.x, wid = tid >> 6, lane = tid & 63;
  const int wm = wid >> 1, wn = wid & 1;
  const u16* Bg = at + (size_t)b*S_N*C_N;
  const f32x4 vzero = {0.f,0.f,0.f,0.f};
  f32x4 acc[4][4];
  #pragma unroll
  for (int i=0;i<4;i++)
    #pragma unroll
    for (int j=0;j<4;j++) acc[i][j] = vzero;

  const int arow = lane >> 2, aslot = (lane & 3) * 8;
  for (int k0 = 0; k0 < C_N; k0 += 32) {
    __syncthreads();
    #pragma unroll
    for (int i = 0; i < 2; i++) {
      int r = wid*32 + i*16 + arow;
      gll16(pwb + (size_t)(m0+r)*C_N + k0 + aslot, &Ash[(wid*32+i*16)*32]);
      gll16(Bg  + (size_t)(n0+r)*C_N + k0 + aslot, &Bsh[(wid*32+i*16)*32]);
    }
    __syncthreads();
    bf16x8 aF[4], bF[4];
    #pragma unroll
    for (int mi=0;mi<4;mi++)
      aF[mi] = *(const bf16x8*)&Ash[(wm*64+mi*16+(lane&15))*32 + (lane>>4)*8];
    #pragma unroll
    for (int ni=0;ni<4;ni++)
      bF[ni] = *(const bf16x8*)&Bsh[(wn*64+ni*16+(lane&15))*32 + (lane>>4)*8];
    #pragma unroll
    for (int mi=0;mi<4;mi++)
      #pragma unroll
      for (int ni=0;ni<4;ni++)
        acc[mi][ni] = __builtin_amdgcn_mfma_f32_16x16x32_bf16(aF[mi], bF[ni], acc[mi][ni], 0, 0, 0);
  }

  #pragma unroll
  for (int mi=0;mi<4;mi++) {
    #pragma unroll
    for (int ni=0;ni<4;ni++) {
      int ss = n0 + wn*64 + ni*16 + (lane & 15);
      #pragma unroll
      for (int r=0;r<4;r++) {
        int o = m0 + wm*64 + mi*16 + (lane>>4)*4 + r;
        size_t idx = ((size_t)b*C_N + o)*S_N + ss;
        out[idx] = acc[mi][ni][r] + bp[o] + x[idx];
      }
    }
  }
}

extern "C" void kernel_launch(void* const* d_in, const int* in_sizes, int n_in,
                              void* d_out, int out_size, void* d_ws, size_t ws_size,
                              hipStream_t stream) {
  const float* x     = (const float*)d_in[0];
  const float* nw    = (const float*)d_in[1];
  const float* nb    = (const float*)d_in[2];
  const float* qkvw  = (const float*)d_in[3];
  const float* qkvb  = (const float*)d_in[4];
  const float* projw = (const float*)d_in[5];
  const float* projb = (const float*)d_in[6];
  float* out = (float*)d_out;

  char* ws = (char*)d_ws;
  float* stats = (float*)ws;                              //   4 KB
  u16* h_t = (u16*)(ws + 4096);                           //  16 MB  [B][S][C]
  u16* qw  = (u16*)(ws + 4096 + 16777216);                // 1.5 MB  [1536][512]
  u16* pw  = (u16*)((char*)qw + 1572864);                 // 0.5 MB  [512][512]
  u16* Qp  = (u16*)((char*)pw + 524288);                  //  16 MB  [B][NH][S][HD]
  u16* Kp  = (u16*)((char*)Qp + 16777216);                //  16 MB  [B][NH][S][HD]
  u16* Vp  = (u16*)((char*)Kp + 16777216);                //  16 MB  [B][NH][HD][S]
  u16* at  = (u16*)((char*)Vp + 16777216);                //  16 MB  [B][S][C]

  gn_stats  <<<512, 256, 0, stream>>>(x, stats);
  gn_apply_t<<<dim3(16,16,16), 256, 0, stream>>>(x, stats, nw, nb, h_t);
  cvt_bf16_k<<<768, 256, 0, stream>>>(qkvw, qw, 196608);
  cvt_bf16_k<<<256, 256, 0, stream>>>(projw, pw, 65536);
  gemm_qkv  <<<dim3(12,8,16), 256, 0, stream>>>(h_t, qw, qkvb, Qp, Kp, Vp);
  attn_fwd  <<<dim3(8,8,16), 256, 0, stream>>>(Qp, Kp, Vp, at);
  gemm_proj <<<dim3(8,4,16), 256, 0, stream>>>(pw, at, projb, x, out);
}

// Round 6
// 319.276 us; speedup vs baseline: 1.0352x; 1.0352x over previous
//
#include <hip/hip_runtime.h>
#include <hip/hip_bf16.h>
#include <stdint.h>

#define B_N 16
#define C_N 512
#define S_N 1024
#define G_N 32
#define NH  8
#define HD  64

typedef __attribute__((ext_vector_type(8))) short bf16x8;
typedef __attribute__((ext_vector_type(4))) float f32x4;
typedef __attribute__((ext_vector_type(16))) float f32x16;
typedef unsigned short u16;
typedef unsigned int   u32;
typedef __attribute__((ext_vector_type(4))) u16 u16x4;
typedef __attribute__((ext_vector_type(4))) u32 u32x4;

__device__ __forceinline__ u16 f2bf(float f) {
  u32 u = __builtin_bit_cast(u32, f);
  u32 r = (u + 0x7fffu + ((u >> 16) & 1u)) >> 16;   // RNE
  return (u16)r;
}

// packed f32x2 -> bf16x2 (compiler emits v_cvt_pk_bf16_f32); a -> low 16
__device__ __forceinline__ u32 pk2(float a, float b) {
  __hip_bfloat162 h = __float22bfloat162_rn(make_float2(a, b));
  u32 r; __builtin_memcpy(&r, &h, 4);
  return r;
}

__device__ __forceinline__ void gll16(const void* g, void* l) {
  __builtin_amdgcn_global_load_lds((const __attribute__((address_space(1))) u32*)g,
                                   (__attribute__((address_space(3))) u32*)l, 16, 0, 0);
}

// ---------------- GroupNorm stats: one block per (b,g) ----------------
__global__ __launch_bounds__(256) void gn_stats(const float* __restrict__ x,
                                                float* __restrict__ stats) {
  const int bg = blockIdx.x;                    // b*32+g
  const float4* xv = (const float4*)(x + (size_t)bg * (16 * S_N));
  float s = 0.f, ss = 0.f;
  for (int i = threadIdx.x; i < 4096; i += 256) {
    float4 v = xv[i];
    s  += v.x + v.y + v.z + v.w;
    ss += v.x*v.x + v.y*v.y + v.z*v.z + v.w*v.w;
  }
  #pragma unroll
  for (int m = 1; m < 64; m <<= 1) { s += __shfl_xor(s, m); ss += __shfl_xor(ss, m); }
  __shared__ float red[2][4];
  const int wid = threadIdx.x >> 6;
  if ((threadIdx.x & 63) == 0) { red[0][wid] = s; red[1][wid] = ss; }
  __syncthreads();
  if (threadIdx.x == 0) {
    float S1 = red[0][0]+red[0][1]+red[0][2]+red[0][3];
    float S2 = red[1][0]+red[1][1]+red[1][2]+red[1][3];
    float mean = S1 * (1.f/16384.f);
    float var  = S2 * (1.f/16384.f) - mean*mean;
    stats[bg*2]   = mean;
    stats[bg*2+1] = rsqrtf(var + 1e-5f);
  }
}

// ------------- normalize + transpose -> h_t[b][s][c] (bf16) -------------
__global__ __launch_bounds__(256) void gn_apply_t(const float* __restrict__ x,
                                                  const float* __restrict__ stats,
                                                  const float* __restrict__ nw,
                                                  const float* __restrict__ nb,
                                                  u16* __restrict__ h_t) {
  const int c0 = blockIdx.x * 32, s0 = blockIdx.y * 64, b = blockIdx.z;
  __shared__ u16 tile[32][68];
  const int t = threadIdx.x;
  #pragma unroll
  for (int i = 0; i < 2; i++) {
    int idx4 = (i*256 + t) * 4;
    int cr = idx4 >> 6, sr = idx4 & 63;
    int c = c0 + cr;
    float4 v = *(const float4*)&x[((size_t)b*C_N + c)*S_N + s0 + sr];
    int bg = b*G_N + (c >> 4);
    float mean = stats[bg*2], rstd = stats[bg*2+1];
    float w = nw[c]*rstd;
    float bb = nb[c] - mean*w;
    tile[cr][sr]   = f2bf(v.x*w + bb);
    tile[cr][sr+1] = f2bf(v.y*w + bb);
    tile[cr][sr+2] = f2bf(v.z*w + bb);
    tile[cr][sr+3] = f2bf(v.w*w + bb);
  }
  __syncthreads();
  #pragma unroll
  for (int i = 0; i < 2; i++) {
    int idx = i*256 + t;
    int sr = idx >> 3;
    int cr4 = (idx & 7) * 4;
    u16x4 v = { tile[cr4][sr], tile[cr4+1][sr], tile[cr4+2][sr], tile[cr4+3][sr] };
    *(u16x4*)&h_t[((size_t)b*S_N + s0 + sr)*C_N + c0 + cr4] = v;
  }
}

// ---------------- fp32 -> bf16 weight convert ----------------
__global__ __launch_bounds__(256) void cvt_bf16_k(const float* __restrict__ src,
                                                  u16* __restrict__ dst, int n4) {
  int i = blockIdx.x*256 + threadIdx.x;
  if (i < n4) {
    float4 v = ((const float4*)src)[i];
    u16x4 r = { f2bf(v.x), f2bf(v.y), f2bf(v.z), f2bf(v.w) };
    ((u16x4*)dst)[i] = r;
  }
}

// ---------------- GEMM-1: qkv = h_t @ qkv_w^T, scatter to Q/K/V packs ----------------
__global__ __launch_bounds__(256) void gemm_qkv(const u16* __restrict__ h_t,
                                                const u16* __restrict__ wq,
                                                const float* __restrict__ bq,
                                                u16* __restrict__ Qp,
                                                u16* __restrict__ Kp,
                                                u16* __restrict__ Vp) {
  __shared__ u16 Ash[128*32];
  __shared__ u16 Bsh[128*32];
  const int n0 = blockIdx.x*128, m0 = blockIdx.y*128, b = blockIdx.z;
  const int tid = threadIdx.x, wid = tid >> 6, lane = tid & 63;
  const int wm = wid >> 1, wn = wid & 1;
  const u16* Ag = h_t + (size_t)b*S_N*C_N;
  const f32x4 vzero = {0.f,0.f,0.f,0.f};
  f32x4 acc[4][4];
  #pragma unroll
  for (int i=0;i<4;i++)
    #pragma unroll
    for (int j=0;j<4;j++) acc[i][j] = vzero;

  const int arow = lane >> 2, aslot = (lane & 3) * 8;
  for (int k0 = 0; k0 < C_N; k0 += 32) {
    __syncthreads();
    #pragma unroll
    for (int i = 0; i < 2; i++) {
      int r = wid*32 + i*16 + arow;
      gll16(Ag + (size_t)(m0+r)*C_N + k0 + aslot, &Ash[(wid*32+i*16)*32]);
      gll16(wq + (size_t)(n0+r)*C_N + k0 + aslot, &Bsh[(wid*32+i*16)*32]);
    }
    __syncthreads();
    bf16x8 aF[4], bF[4];
    #pragma unroll
    for (int mi=0;mi<4;mi++)
      aF[mi] = *(const bf16x8*)&Ash[(wm*64+mi*16+(lane&15))*32 + (lane>>4)*8];
    #pragma unroll
    for (int ni=0;ni<4;ni++)
      bF[ni] = *(const bf16x8*)&Bsh[(wn*64+ni*16+(lane&15))*32 + (lane>>4)*8];
    #pragma unroll
    for (int mi=0;mi<4;mi++)
      #pragma unroll
      for (int ni=0;ni<4;ni++)
        acc[mi][ni] = __builtin_amdgcn_mfma_f32_16x16x32_bf16(aF[mi], bF[ni], acc[mi][ni], 0, 0, 0);
  }

  #pragma unroll
  for (int mi=0;mi<4;mi++) {
    #pragma unroll
    for (int ni=0;ni<4;ni++) {
      int o = n0 + wn*64 + ni*16 + (lane & 15);
      float bias = bq[o];
      int sec = o >> 9;
      int oo  = o & 511;
      int hh  = oo >> 6, d = oo & 63;
      size_t bh = (size_t)(b*NH + hh);
      #pragma unroll
      for (int r=0;r<4;r++) {
        int s = m0 + wm*64 + mi*16 + (lane>>4)*4 + r;
        u16 bv = f2bf(acc[mi][ni][r] + bias);
        if (sec == 0)      Qp[(bh*S_N + s)*HD + d] = bv;
        else if (sec == 1) Kp[(bh*S_N + s)*HD + d] = bv;
        else               Vp[(bh*HD + d)*S_N + s] = bv;
      }
    }
  }
}

// ---------------- flash attention, swapped-operand 32x32, reg-pipelined ----------------
// K-frags double-buffered in registers (prefetch next tile before softmax);
// V loads issued before QK^T so softmax covers their latency. Defer-rescale (T13).
__device__ __forceinline__ void attn_tile(const u16* __restrict__ Kb,
                                          const u16* __restrict__ Vb,
                                          const bf16x8 (&qf)[4],
                                          const bf16x8 (&kcur)[2][4],
                                          bf16x8 (&knext)[2][4],
                                          f32x16 (&oacc)[2],
                                          float& m_run, float& l_run,
                                          int t0, int l31, int hi) {
  const float SC2 = 0.18033688011112042f;   // (1/sqrt(64)) * log2(e)
  const int tn = (t0 + 64) & (S_N - 1);     // next tile (wraps harmlessly at end)

  // issue V loads (this tile) and K loads (next tile) first — latency hidden under softmax
  bf16x8 vF[2][4];
  #pragma unroll
  for (int dt=0;dt<2;dt++)
    #pragma unroll
    for (int ks=0;ks<4;ks++)
      vF[dt][ks] = *(const bf16x8*)&Vb[(size_t)(dt*32 + l31)*S_N + t0 + ks*16 + hi*8];
  #pragma unroll
  for (int tt=0;tt<2;tt++)
    #pragma unroll
    for (int kt=0;kt<4;kt++)
      knext[tt][kt] = *(const bf16x8*)&Kb[(size_t)(tn + tt*32 + l31)*HD + kt*16 + hi*8];

  // QK^T from prefetched kcur: st[tt][reg] = S[t][s], t=(reg&3)+8*(reg>>2)+4*hi+32*tt
  f32x16 st[2];
  #pragma unroll
  for (int tt=0;tt<2;tt++)
    #pragma unroll
    for (int i=0;i<16;i++) st[tt][i] = 0.f;
  #pragma unroll
  for (int tt=0;tt<2;tt++)
    #pragma unroll
    for (int kt=0;kt<4;kt++)
      st[tt] = __builtin_amdgcn_mfma_f32_32x32x16_bf16(kcur[tt][kt], qf[kt], st[tt], 0, 0, 0);

  // row max over 64 t
  float mx[16];
  #pragma unroll
  for (int i=0;i<16;i++) mx[i] = fmaxf(st[0][i], st[1][i]);
  #pragma unroll
  for (int off=8; off; off>>=1)
    #pragma unroll
    for (int i=0;i<8;i++) if (i < off) mx[i] = fmaxf(mx[i], mx[i+off]);
  float tmax = fmaxf(mx[0], __shfl_xor(mx[0], 32));

  // defer-rescale: only pay the O-rescale when max moved by > 64 (8 nats after *0.125 scale)
  if (__any(tmax > m_run + 64.0f)) {
    float mnew  = fmaxf(m_run, tmax);
    float alpha = exp2f((m_run - mnew) * SC2);
    m_run = mnew;
    l_run *= alpha;
    #pragma unroll
    for (int dt=0;dt<2;dt++)
      #pragma unroll
      for (int i=0;i<16;i++) oacc[dt][i] *= alpha;
  }
  float mc = m_run * SC2;

  // P = exp2(S*SC2 - mc), in place
  #pragma unroll
  for (int tt=0;tt<2;tt++)
    #pragma unroll
    for (int i=0;i<16;i++)
      st[tt][i] = exp2f(fmaf(st[tt][i], SC2, -mc));

  // row sum
  float sm[16];
  #pragma unroll
  for (int i=0;i<16;i++) sm[i] = st[0][i] + st[1][i];
  #pragma unroll
  for (int off=8; off; off>>=1)
    #pragma unroll
    for (int i=0;i<8;i++) if (i < off) sm[i] += sm[i+off];
  l_run += sm[0] + __shfl_xor(sm[0], 32);

  // assemble P^T B-fragments: pa[ks] elem j <-> t = ks*16 + hi*8 + j
  // hi=0 keeps w0,w1 and receives partner w0,w1; hi=1 keeps w2,w3, receives partner w2,w3
  u32x4 paw[4];
  #pragma unroll
  for (int ks=0;ks<4;ks++) {
    float p0 = st[ks>>1][(ks&1)*8+0], p1 = st[ks>>1][(ks&1)*8+1];
    float p2 = st[ks>>1][(ks&1)*8+2], p3 = st[ks>>1][(ks&1)*8+3];
    float p4 = st[ks>>1][(ks&1)*8+4], p5 = st[ks>>1][(ks&1)*8+5];
    float p6 = st[ks>>1][(ks&1)*8+6], p7 = st[ks>>1][(ks&1)*8+7];
    u32 w0 = pk2(p0, p1);
    u32 w1 = pk2(p2, p3);
    u32 w2 = pk2(p4, p5);
    u32 w3 = pk2(p6, p7);
    u32 s0 = hi ? w0 : w2;               // word my partner needs
    u32 s1 = hi ? w1 : w3;
    u32 r0 = (u32)__shfl_xor((int)s0, 32);
    u32 r1 = (u32)__shfl_xor((int)s1, 32);
    u32x4 w = { hi ? r0 : w0, hi ? r1 : w1, hi ? w2 : r0, hi ? w3 : r1 };
    paw[ks] = w;
  }

  // O^T[dt] += sum_ks V^T_frag(dt,ks) * pa[ks]
  #pragma unroll
  for (int dt=0;dt<2;dt++)
    #pragma unroll
    for (int ks=0;ks<4;ks++)
      oacc[dt] = __builtin_amdgcn_mfma_f32_32x32x16_bf16(vF[dt][ks], __builtin_bit_cast(bf16x8, paw[ks]), oacc[dt], 0, 0, 0);
}

__global__ __launch_bounds__(256) void attn_fwd(const u16* __restrict__ Qp,
                                                const u16* __restrict__ Kp,
                                                const u16* __restrict__ Vp,
                                                u16* __restrict__ at) {
  const int hh = blockIdx.x, q0 = blockIdx.y*128, b = blockIdx.z;
  const int tid = threadIdx.x, wid = tid >> 6, lane = tid & 63;
  const int l31 = lane & 31, hi = lane >> 5;
  const size_t bh = (size_t)(b*NH + hh);
  const u16* Qb = Qp + bh*(S_N*HD);
  const u16* Kb = Kp + bh*(S_N*HD);
  const u16* Vb = Vp + bh*(HD*S_N);
  const int s = q0 + wid*32 + l31;          // this lane's s-row

  // Q B-fragments: Q[s][kt*16 + hi*8 + j]
  bf16x8 qf[4];
  #pragma unroll
  for (int kt=0;kt<4;kt++)
    qf[kt] = *(const bf16x8*)&Qb[(size_t)s*HD + kt*16 + hi*8];

  f32x16 oacc[2];
  #pragma unroll
  for (int dt=0;dt<2;dt++)
    #pragma unroll
    for (int i=0;i<16;i++) oacc[dt][i] = 0.f;
  float m_run = -1e30f, l_run = 0.f;

  // prefetch K for tile 0
  bf16x8 kA[2][4], kB[2][4];
  #pragma unroll
  for (int tt=0;tt<2;tt++)
    #pragma unroll
    for (int kt=0;kt<4;kt++)
      kA[tt][kt] = *(const bf16x8*)&Kb[(size_t)(tt*32 + l31)*HD + kt*16 + hi*8];

  #pragma unroll 1
  for (int t0 = 0; t0 < S_N; t0 += 128) {
    attn_tile(Kb, Vb, qf, kA, kB, oacc, m_run, l_run, t0,      l31, hi);
    attn_tile(Kb, Vb, qf, kB, kA, oacc, m_run, l_run, t0 + 64, l31, hi);
  }

  // epilogue: O^T[d][s]/l -> at[b][s][h*64+d]; d = (reg&3)+8*(reg>>2)+4*hi+32*dt
  float inv = 1.0f / l_run;
  #pragma unroll
  for (int dt=0;dt<2;dt++)
    #pragma unroll
    for (int qd=0;qd<4;qd++) {
      int dbase = 4*hi + 8*qd + 32*dt;
      u16x4 o;
      #pragma unroll
      for (int j=0;j<4;j++) o[j] = f2bf(oacc[dt][qd*4+j] * inv);
      *(u16x4*)&at[((size_t)b*S_N + s)*C_N + hh*HD + dbase] = o;
    }
}

// ---------------- GEMM-2: out = proj_w @ attn + bias + x ----------------
__global__ __launch_bounds__(256) void gemm_proj(const u16* __restrict__ pwb,
                                                 const u16* __restrict__ at,
                                                 const float* __restrict__ bp,
                                                 const float* __restrict__ x,
                                                 float* __restrict__ out) {
  __shared__ u16 Ash[128*32];
  __shared__ u16 Bsh[128*32];
  const int n0 = blockIdx.x*128, m0 = blockIdx.y*128, b = blockIdx.z;
  const int tid = threadIdx.x, wid = tid >> 6, lane = tid & 63;
  const int wm = wid >> 1, wn = wid & 1;
  const u16* Bg = at + (size_t)b*S_N*C_N;
  const f32x4 vzero = {0.f,0.f,0.f,0.f};
  f32x4 acc[4][4];
  #pragma unroll
  for (int i=0;i<4;i++)
    #pragma unroll
    for (int j=0;j<4;j++) acc[i][j] = vzero;

  const int arow = lane >> 2, aslot = (lane & 3) * 8;
  for (int k0 = 0; k0 < C_N; k0 += 32) {
    __syncthreads();
    #pragma unroll
    for (int i = 0; i < 2; i++) {
      int r = wid*32 + i*16 + arow;
      gll16(pwb + (size_t)(m0+r)*C_N + k0 + aslot, &Ash[(wid*32+i*16)*32]);
      gll16(Bg  + (size_t)(n0+r)*C_N + k0 + aslot, &Bsh[(wid*32+i*16)*32]);
    }
    __syncthreads();
    bf16x8 aF[4], bF[4];
    #pragma unroll
    for (int mi=0;mi<4;mi++)
      aF[mi] = *(const bf16x8*)&Ash[(wm*64+mi*16+(lane&15))*32 + (lane>>4)*8];
    #pragma unroll
    for (int ni=0;ni<4;ni++)
      bF[ni] = *(const bf16x8*)&Bsh[(wn*64+ni*16+(lane&15))*32 + (lane>>4)*8];
    #pragma unroll
    for (int mi=0;mi<4;mi++)
      #pragma unroll
      for (int ni=0;ni<4;ni++)
        acc[mi][ni] = __builtin_amdgcn_mfma_f32_16x16x32_bf16(aF[mi], bF[ni], acc[mi][ni], 0, 0, 0);
  }

  #pragma unroll
  for (int mi=0;mi<4;mi++) {
    #pragma unroll
    for (int ni=0;ni<4;ni++) {
      int ss = n0 + wn*64 + ni*16 + (lane & 15);
      #pragma unroll
      for (int r=0;r<4;r++) {
        int o = m0 + wm*64 + mi*16 + (lane>>4)*4 + r;
        size_t idx = ((size_t)b*C_N + o)*S_N + ss;
        out[idx] = acc[mi][ni][r] + bp[o] + x[idx];
      }
    }
  }
}

extern "C" void kernel_launch(void* const* d_in, const int* in_sizes, int n_in,
                              void* d_out, int out_size, void* d_ws, size_t ws_size,
                              hipStream_t stream) {
  const float* x     = (const float*)d_in[0];
  const float* nw    = (const float*)d_in[1];
  const float* nb    = (const float*)d_in[2];
  const float* qkvw  = (const float*)d_in[3];
  const float* qkvb  = (const float*)d_in[4];
  const float* projw = (const float*)d_in[5];
  const float* projb = (const float*)d_in[6];
  float* out = (float*)d_out;

  char* ws = (char*)d_ws;
  float* stats = (float*)ws;                              //   4 KB
  u16* h_t = (u16*)(ws + 4096);                           //  16 MB  [B][S][C]
  u16* qw  = (u16*)(ws + 4096 + 16777216);                // 1.5 MB  [1536][512]
  u16* pw  = (u16*)((char*)qw + 1572864);                 // 0.5 MB  [512][512]
  u16* Qp  = (u16*)((char*)pw + 524288);                  //  16 MB  [B][NH][S][HD]
  u16* Kp  = (u16*)((char*)Qp + 16777216);                //  16 MB  [B][NH][S][HD]
  u16* Vp  = (u16*)((char*)Kp + 16777216);                //  16 MB  [B][NH][HD][S]
  u16* at  = (u16*)((char*)Vp + 16777216);                //  16 MB  [B][S][C]

  gn_stats  <<<512, 256, 0, stream>>>(x, stats);
  gn_apply_t<<<dim3(16,16,16), 256, 0, stream>>>(x, stats, nw, nb, h_t);
  cvt_bf16_k<<<768, 256, 0, stream>>>(qkvw, qw, 196608);
  cvt_bf16_k<<<256, 256, 0, stream>>>(projw, pw, 65536);
  gemm_qkv  <<<dim3(12,8,16), 256, 0, stream>>>(h_t, qw, qkvb, Qp, Kp, Vp);
  attn_fwd  <<<dim3(8,8,16), 256, 0, stream>>>(Qp, Kp, Vp, at);
  gemm_proj <<<dim3(8,4,16), 256, 0, stream>>>(pw, at, projb, x, out);
}